// Round 1
// baseline (157.936 us; speedup 1.0000x reference)
//
#include <hip/hip_runtime.h>
#include <hip/hip_bf16.h>

#define N 8192
#define D 128
#define HALF_N 4096
// z pre-scaled by sqrt(10 * log2(e)) so acc = z.z^T is sim in log2 domain:
// exp(sim) == exp2(acc). pos (= sim) recovered as acc * ln2 on its single tile.
#define SQRT_SCALE_LOG2E 3.79828236f
#define LN2 0.693147180559945f

#define BLOCK_ROWS 256   // 4 waves * 64 rows each
#define COLS_PER_ITER 64
#define COL_SPLITS 32
#define COLS_PER_BLOCK (N / COL_SPLITS)          // 256
#define ITERS (COLS_PER_BLOCK / COLS_PER_ITER)   // 4

typedef short frag8 __attribute__((ext_vector_type(8)));
typedef float f32x4 __attribute__((ext_vector_type(4)));
typedef const __attribute__((address_space(1))) unsigned int* gbl_u32p;
typedef __attribute__((address_space(3))) unsigned int* lds_u32p;

// ws layout (floats): pos[N] | psums[COL_SPLITS][N] | acc0 | pad | z (bf16)
#define OFF_POS    0
#define OFF_PSUMS  (N)
#define OFF_ACC    (N + COL_SPLITS * N)
#define OFF_Z_BYTES ((OFF_ACC + 64) * 4)

__device__ __forceinline__ unsigned short f2bf(float f) {
    unsigned int u = __float_as_uint(f);
    u += 0x7FFFu + ((u >> 16) & 1u);
    return (unsigned short)(u >> 16);
}

// K1: z = sqrt(10*log2e) * x / max(||x||, eps)  (bf16); zero scalar acc.
__global__ __launch_bounds__(256) void k_normalize(const float* __restrict__ x,
                                                   unsigned short* __restrict__ z,
                                                   float* __restrict__ acc0) {
    const int row  = blockIdx.x * 4 + (threadIdx.x >> 6);
    const int lane = threadIdx.x & 63;
    float2 v = ((const float2*)x)[row * 64 + lane];
    float s = v.x * v.x + v.y * v.y;
    #pragma unroll
    for (int m = 32; m >= 1; m >>= 1) s += __shfl_xor(s, m);
    float inv = SQRT_SCALE_LOG2E / fmaxf(sqrtf(s), 1e-8f);
    ushort2 o;
    o.x = f2bf(v.x * inv);
    o.y = f2bf(v.y * inv);
    ((ushort2*)z)[row * 64 + lane] = o;
    if (blockIdx.x == 0 && threadIdx.x == 0) acc0[0] = 0.0f;
}

// Stage one 64x128 bf16 tile into LDS via global_load_lds (linear dest,
// XOR-swizzled source so the ds_read side can swizzle conflict-free).
// stg_src[u] = lane's source offset (ushorts) within the tile, precomputed.
__device__ __forceinline__ void stage_tile(const unsigned short* __restrict__ z,
                                           unsigned short* ldsbuf,
                                           int colbase, int wave,
                                           const int* stg_src) {
    const unsigned short* zc = z + (size_t)colbase * D;
    #pragma unroll
    for (int u = 0; u < 4; ++u) {
        // wave-uniform LDS base; HW writes base + lane*16B (row = +lane>>4, chunk = lane&15)
        __builtin_amdgcn_global_load_lds((gbl_u32p)(zc + stg_src[u]),
                                         (lds_u32p)(ldsbuf + (wave * 16 + u * 4) * D),
                                         16, 0, 0);
    }
}

// K2: fused z.z^T + exp2 + per-row partial sums.
// m97-style: double-buffered LDS, global_load_lds staging issued before compute
// (latency hides under MFMA/exp2), ONE barrier per iter, 4 blocks/CU.
__global__ __launch_bounds__(256, 4) void k_simloss(const unsigned short* __restrict__ z,
                                                    float* __restrict__ psums,
                                                    float* __restrict__ pos) {
    __shared__ unsigned short lds[2][COLS_PER_ITER * D];  // 2 x 16 KB, linear (swizzle via src perm)

    const int tid  = threadIdx.x;
    const int wave = tid >> 6;
    const int lane = tid & 63;
    const int l15  = lane & 15;
    const int quad = lane >> 4;
    const int l7   = l15 & 7;
    const int wrow = blockIdx.x * BLOCK_ROWS + wave * 64;
    const int colbase0 = blockIdx.y * COLS_PER_BLOCK;
    const int posbase  = (wrow + HALF_N) & (N - 1);

    // Staging source offsets: LDS slot (r, chunk'=l15) must hold global chunk (l15 ^ (r&7)).
    // wave*16 = 0 mod 8, so r&7 = (u*4 + lane>>4) & 7.
    int stg_src[4];
    #pragma unroll
    for (int u = 0; u < 4; ++u) {
        int r = wave * 16 + u * 4 + (lane >> 4);
        stg_src[u] = r * D + ((l15 ^ (r & 7)) << 3);
    }

    // B-frag read offsets: data k-chunk (quad+4q) of row l15 sits at slot (quad+4q)^(l15&7).
    // Bank check: 8 lanes per 16B slot-phase -> 2 lanes/bank = free (m136).
    int boff[4];
    #pragma unroll
    for (int q = 0; q < 4; ++q)
        boff[q] = l15 * D + (((quad + 4 * q) ^ l7) << 3);

    // A fragments: 4 row-stripes of 16 x K=128, register-resident (64 VGPRs).
    frag8 a[4][4];
    #pragma unroll
    for (int s = 0; s < 4; ++s) {
        const uint4* p = (const uint4*)&z[(wrow + s * 16 + l15) * D + quad * 8];
        #pragma unroll
        for (int q = 0; q < 4; ++q) {
            uint4 t = p[q * 4];
            a[s][q] = *(frag8*)&t;
        }
    }

    float sums[4][4];
    #pragma unroll
    for (int s = 0; s < 4; ++s)
        #pragma unroll
        for (int r = 0; r < 4; ++r) sums[s][r] = 0.0f;

    stage_tile(z, &lds[0][0], colbase0, wave, stg_src);
    __syncthreads();  // drains vmcnt -> buf0 ready

    for (int it = 0; it < ITERS; ++it) {
        // Issue next tile's loads NOW; they fly while we do MFMA+exp2 below.
        if (it + 1 < ITERS)
            stage_tile(z, &lds[(it + 1) & 1][0], colbase0 + (it + 1) * COLS_PER_ITER, wave, stg_src);

        const int colbase = colbase0 + it * COLS_PER_ITER;
        const bool isDiag = (colbase == wrow);
        const bool isPos  = (colbase == posbase);
        const unsigned short* lb = &lds[it & 1][0];

        #pragma unroll
        for (int c = 0; c < 4; ++c) {
            f32x4 acc[4];
            #pragma unroll
            for (int s = 0; s < 4; ++s) acc[s] = (f32x4){0.f, 0.f, 0.f, 0.f};
            #pragma unroll
            for (int q = 0; q < 4; ++q) {
                frag8 b = *(const frag8*)&lb[c * (16 * D) + boff[q]];
                #pragma unroll
                for (int s = 0; s < 4; ++s)
                    acc[s] = __builtin_amdgcn_mfma_f32_16x16x32_bf16(a[s][q], b, acc[s], 0, 0, 0);
            }
            if (isDiag | isPos) {
                // special tile: local diagonal element at c==s, l15==quad*4+r
                #pragma unroll
                for (int s = 0; s < 4; ++s)
                    #pragma unroll
                    for (int r = 0; r < 4; ++r) {
                        float v = acc[s][r];
                        float e = __builtin_amdgcn_exp2f(v);
                        if (c == s) {  // compile-time
                            bool hit = (l15 == quad * 4 + r);
                            if (isDiag && hit) e = 0.0f;
                            if (isPos  && hit) pos[wrow + s * 16 + quad * 4 + r] = v * LN2;
                        }
                        sums[s][r] += e;
                    }
            } else {
                #pragma unroll
                for (int s = 0; s < 4; ++s)
                    #pragma unroll
                    for (int r = 0; r < 4; ++r)
                        sums[s][r] += __builtin_amdgcn_exp2f(acc[s][r]);
            }
        }
        // One barrier per iter: ensures (a) next buf's global_load_lds landed,
        // (b) everyone is done reading buf[it&1] before it gets restaged next iter.
        __syncthreads();
    }

    // Reduce each row-sum across the 16 lanes holding that row; one store per row.
    #pragma unroll
    for (int s = 0; s < 4; ++s)
        #pragma unroll
        for (int r = 0; r < 4; ++r) {
            float v = sums[s][r];
            v += __shfl_xor(v, 1);
            v += __shfl_xor(v, 2);
            v += __shfl_xor(v, 4);
            v += __shfl_xor(v, 8);
            if (l15 == 0)
                psums[blockIdx.y * N + wrow + s * 16 + quad * 4 + r] = v;
        }
}

// K3a: per-row loss = log(sum of partials) - pos; block-reduce; atomic into acc0.
__global__ __launch_bounds__(1024) void k_rowloss(const float* __restrict__ psums,
                                                  const float* __restrict__ pos,
                                                  float* __restrict__ acc0) {
    const int row = blockIdx.x * 1024 + threadIdx.x;
    float t = 0.0f;
    #pragma unroll
    for (int s = 0; s < COL_SPLITS; ++s) t += psums[s * N + row];
    float loss = __logf(t) - pos[row];
    #pragma unroll
    for (int m = 32; m >= 1; m >>= 1) loss += __shfl_xor(loss, m);
    __shared__ float p[16];
    if ((threadIdx.x & 63) == 0) p[threadIdx.x >> 6] = loss;
    __syncthreads();
    if (threadIdx.x == 0) {
        float s = 0.0f;
        #pragma unroll
        for (int w = 0; w < 16; ++w) s += p[w];
        atomicAdd(acc0, s);
    }
}

// K3b: mean.
__global__ void k_final(const float* __restrict__ acc0, float* __restrict__ out) {
    out[0] = acc0[0] * (1.0f / N);
}

extern "C" void kernel_launch(void* const* d_in, const int* in_sizes, int n_in,
                              void* d_out, int out_size, void* d_ws, size_t ws_size,
                              hipStream_t stream) {
    const float* x = (const float*)d_in[0];
    float* wsf   = (float*)d_ws;
    float* pos   = wsf + OFF_POS;
    float* psums = wsf + OFF_PSUMS;
    float* acc0  = wsf + OFF_ACC;
    unsigned short* z = (unsigned short*)((char*)d_ws + OFF_Z_BYTES);

    k_normalize<<<N / 4, 256, 0, stream>>>(x, z, acc0);
    dim3 g2(N / BLOCK_ROWS, COL_SPLITS);  // (32, 32) = 1024 blocks -> 4/CU
    k_simloss<<<g2, 256, 0, stream>>>(z, psums, pos);
    k_rowloss<<<N / 1024, 1024, 0, stream>>>(psums, pos, acc0);
    k_final<<<1, 1, 0, stream>>>(acc0, (float*)d_out);
}

// Round 2
// 82.016 us; speedup vs baseline: 1.9257x; 1.9257x over previous
//
#include <hip/hip_runtime.h>
#include <hip/hip_bf16.h>

#define N 8192
#define D 128
#define HALF_N 4096
// z pre-scaled by sqrt(10 * log2(e)) so acc = z.z^T is sim in log2 domain:
// exp(sim) == exp2(acc). pos (= sim) recovered as acc * ln2 on its single tile.
#define SQRT_SCALE_LOG2E 3.79828236f
#define LN2 0.693147180559945f

#define BLOCK_ROWS 256   // 4 waves * 64 rows each
#define COLS_PER_ITER 64
#define COL_SPLITS 16
#define COLS_PER_BLOCK (N / COL_SPLITS)          // 512
#define ITERS (COLS_PER_BLOCK / COLS_PER_ITER)   // 8

typedef short frag8 __attribute__((ext_vector_type(8)));
typedef float f32x4 __attribute__((ext_vector_type(4)));
typedef const __attribute__((address_space(1))) unsigned int* gbl_u32p;
typedef __attribute__((address_space(3))) unsigned int* lds_u32p;

// ws layout (floats): pos[N] | psums[COL_SPLITS][N] | acc0 | pad | z (bf16)
#define OFF_POS    0
#define OFF_PSUMS  (N)
#define OFF_ACC    (N + COL_SPLITS * N)
#define OFF_Z_BYTES ((OFF_ACC + 64) * 4)

__device__ __forceinline__ unsigned short f2bf(float f) {
    unsigned int u = __float_as_uint(f);
    u += 0x7FFFu + ((u >> 16) & 1u);
    return (unsigned short)(u >> 16);
}

// K1: z = sqrt(10*log2e) * x / max(||x||, eps)  (bf16); zero scalar acc.
__global__ __launch_bounds__(256) void k_normalize(const float* __restrict__ x,
                                                   unsigned short* __restrict__ z,
                                                   float* __restrict__ acc0) {
    const int row  = blockIdx.x * 4 + (threadIdx.x >> 6);
    const int lane = threadIdx.x & 63;
    float2 v = ((const float2*)x)[row * 64 + lane];
    float s = v.x * v.x + v.y * v.y;
    #pragma unroll
    for (int m = 32; m >= 1; m >>= 1) s += __shfl_xor(s, m);
    float inv = SQRT_SCALE_LOG2E / fmaxf(sqrtf(s), 1e-8f);
    ushort2 o;
    o.x = f2bf(v.x * inv);
    o.y = f2bf(v.y * inv);
    ((ushort2*)z)[row * 64 + lane] = o;
    if (blockIdx.x == 0 && threadIdx.x == 0) acc0[0] = 0.0f;
}

// Stage one 64x128 bf16 tile into LDS via global_load_lds (linear dest,
// XOR-swizzled source so the ds_read side can swizzle conflict-free).
// stg_src[u] = lane's source offset (ushorts) within the tile, precomputed.
__device__ __forceinline__ void stage_tile(const unsigned short* __restrict__ z,
                                           unsigned short* ldsbuf,
                                           int colbase, int wave,
                                           const int* stg_src) {
    const unsigned short* zc = z + (size_t)colbase * D;
    #pragma unroll
    for (int u = 0; u < 4; ++u) {
        // wave-uniform LDS base; HW writes base + lane*16B (row = +lane>>4, chunk = lane&15)
        __builtin_amdgcn_global_load_lds((gbl_u32p)(zc + stg_src[u]),
                                         (lds_u32p)(ldsbuf + (wave * 16 + u * 4) * D),
                                         16, 0, 0);
    }
}

// K2: fused z.z^T + exp2 + per-row partial sums.
// m97-style: double-buffered LDS, global_load_lds staging issued before compute
// (latency hides under MFMA/exp2), ONE barrier per iter.
// launch_bounds(256,2): 256-VGPR budget — (256,4) capped at 64 VGPRs and spilled
// 300 MB/dispatch to scratch (round-1 post-mortem: WRITE_SIZE 203MB, MfmaUtil 7.5%).
__global__ __launch_bounds__(256, 2) void k_simloss(const unsigned short* __restrict__ z,
                                                    float* __restrict__ psums,
                                                    float* __restrict__ pos) {
    __shared__ unsigned short lds[2][COLS_PER_ITER * D];  // 2 x 16 KB, linear (swizzle via src perm)

    const int tid  = threadIdx.x;
    const int wave = tid >> 6;
    const int lane = tid & 63;
    const int l15  = lane & 15;
    const int quad = lane >> 4;
    const int l7   = l15 & 7;
    const int wrow = blockIdx.x * BLOCK_ROWS + wave * 64;
    const int colbase0 = blockIdx.y * COLS_PER_BLOCK;
    const int posbase  = (wrow + HALF_N) & (N - 1);

    // Staging source offsets: LDS slot (r, chunk'=l15) must hold global chunk (l15 ^ (r&7)).
    // wave*16 = 0 mod 8, so r&7 = (u*4 + lane>>4) & 7.
    int stg_src[4];
    #pragma unroll
    for (int u = 0; u < 4; ++u) {
        int r = wave * 16 + u * 4 + (lane >> 4);
        stg_src[u] = r * D + ((l15 ^ (r & 7)) << 3);
    }

    // B-frag read offsets: data k-chunk (quad+4q) of row l15 sits at slot (quad+4q)^(l15&7).
    // Bank phases: every 8 consecutive lanes hit 8 distinct 16B phases -> conflict-free.
    int boff[4];
    #pragma unroll
    for (int q = 0; q < 4; ++q)
        boff[q] = l15 * D + (((quad + 4 * q) ^ l7) << 3);

    // A fragments: 4 row-stripes of 16 x K=128, register-resident (64 VGPRs).
    frag8 a[4][4];
    #pragma unroll
    for (int s = 0; s < 4; ++s) {
        const uint4* p = (const uint4*)&z[(wrow + s * 16 + l15) * D + quad * 8];
        #pragma unroll
        for (int q = 0; q < 4; ++q) {
            uint4 t = p[q * 4];
            a[s][q] = *(frag8*)&t;
        }
    }

    float sums[4][4];
    #pragma unroll
    for (int s = 0; s < 4; ++s)
        #pragma unroll
        for (int r = 0; r < 4; ++r) sums[s][r] = 0.0f;

    stage_tile(z, &lds[0][0], colbase0, wave, stg_src);
    __syncthreads();  // drains vmcnt -> buf0 ready

    for (int it = 0; it < ITERS; ++it) {
        // Issue next tile's loads NOW; they fly while we do MFMA+exp2 below.
        if (it + 1 < ITERS)
            stage_tile(z, &lds[(it + 1) & 1][0], colbase0 + (it + 1) * COLS_PER_ITER, wave, stg_src);

        const int colbase = colbase0 + it * COLS_PER_ITER;
        const bool isDiag = (colbase == wrow);
        const bool isPos  = (colbase == posbase);
        const unsigned short* lb = &lds[it & 1][0];

        #pragma unroll
        for (int c = 0; c < 4; ++c) {
            f32x4 acc[4];
            #pragma unroll
            for (int s = 0; s < 4; ++s) acc[s] = (f32x4){0.f, 0.f, 0.f, 0.f};
            #pragma unroll
            for (int q = 0; q < 4; ++q) {
                frag8 b = *(const frag8*)&lb[c * (16 * D) + boff[q]];
                #pragma unroll
                for (int s = 0; s < 4; ++s)
                    acc[s] = __builtin_amdgcn_mfma_f32_16x16x32_bf16(a[s][q], b, acc[s], 0, 0, 0);
            }
            if (isDiag | isPos) {
                // special tile: local diagonal element at c==s, l15==quad*4+r
                #pragma unroll
                for (int s = 0; s < 4; ++s)
                    #pragma unroll
                    for (int r = 0; r < 4; ++r) {
                        float v = acc[s][r];
                        float e = __builtin_amdgcn_exp2f(v);
                        if (c == s) {  // compile-time
                            bool hit = (l15 == quad * 4 + r);
                            if (isDiag && hit) e = 0.0f;
                            if (isPos  && hit) pos[wrow + s * 16 + quad * 4 + r] = v * LN2;
                        }
                        sums[s][r] += e;
                    }
            } else {
                #pragma unroll
                for (int s = 0; s < 4; ++s)
                    #pragma unroll
                    for (int r = 0; r < 4; ++r)
                        sums[s][r] += __builtin_amdgcn_exp2f(acc[s][r]);
            }
        }
        // One barrier per iter: ensures (a) next buf's global_load_lds landed,
        // (b) everyone is done reading buf[it&1] before it gets restaged next iter.
        __syncthreads();
    }

    // Reduce each row-sum across the 16 lanes holding that row; one store per row.
    #pragma unroll
    for (int s = 0; s < 4; ++s)
        #pragma unroll
        for (int r = 0; r < 4; ++r) {
            float v = sums[s][r];
            v += __shfl_xor(v, 1);
            v += __shfl_xor(v, 2);
            v += __shfl_xor(v, 4);
            v += __shfl_xor(v, 8);
            if (l15 == 0)
                psums[blockIdx.y * N + wrow + s * 16 + quad * 4 + r] = v;
        }
}

// K3a: per-row loss = log(sum of partials) - pos; block-reduce; atomic into acc0.
__global__ __launch_bounds__(1024) void k_rowloss(const float* __restrict__ psums,
                                                  const float* __restrict__ pos,
                                                  float* __restrict__ acc0) {
    const int row = blockIdx.x * 1024 + threadIdx.x;
    float t = 0.0f;
    #pragma unroll
    for (int s = 0; s < COL_SPLITS; ++s) t += psums[s * N + row];
    float loss = __logf(t) - pos[row];
    #pragma unroll
    for (int m = 32; m >= 1; m >>= 1) loss += __shfl_xor(loss, m);
    __shared__ float p[16];
    if ((threadIdx.x & 63) == 0) p[threadIdx.x >> 6] = loss;
    __syncthreads();
    if (threadIdx.x == 0) {
        float s = 0.0f;
        #pragma unroll
        for (int w = 0; w < 16; ++w) s += p[w];
        atomicAdd(acc0, s);
    }
}

// K3b: mean.
__global__ void k_final(const float* __restrict__ acc0, float* __restrict__ out) {
    out[0] = acc0[0] * (1.0f / N);
}

extern "C" void kernel_launch(void* const* d_in, const int* in_sizes, int n_in,
                              void* d_out, int out_size, void* d_ws, size_t ws_size,
                              hipStream_t stream) {
    const float* x = (const float*)d_in[0];
    float* wsf   = (float*)d_ws;
    float* pos   = wsf + OFF_POS;
    float* psums = wsf + OFF_PSUMS;
    float* acc0  = wsf + OFF_ACC;
    unsigned short* z = (unsigned short*)((char*)d_ws + OFF_Z_BYTES);

    k_normalize<<<N / 4, 256, 0, stream>>>(x, z, acc0);
    dim3 g2(N / BLOCK_ROWS, COL_SPLITS);  // (32, 16) = 512 blocks -> 2/CU
    k_simloss<<<g2, 256, 0, stream>>>(z, psums, pos);
    k_rowloss<<<N / 1024, 1024, 0, stream>>>(psums, pos, acc0);
    k_final<<<1, 1, 0, stream>>>(acc0, (float*)d_out);
}